// Round 6
// baseline (336.863 us; speedup 1.0000x reference)
//
#include <hip/hip_runtime.h>

// LSTM B=4096 T=512 IN=14 H=28 OUT=2, fp32 in/out.
// Fully wave-autonomous, ZERO barriers, zero cross-wave traffic: each 64-thread
// block is ONE wave owning MB=4 batches end-to-end. Grid 1024 -> 4 waves/CU.
//   A = weights, 7 row-tiles ts: row r -> (gate r&3, unit 4*ts + (r>>2)).
//   B = data, 16 cols = 4 batches x 4 copies (col m -> batch m&3) -> broadcast.
//   C: lane (q,m) reg j of tile ts = gate-j preact, unit 4*ts+q, batch m&3.
//   Gate ownership by COPY cp=m>>2: lane gates tiles {cp, 4+cp} (4+cp<7) ->
//   <=2 gate4/lane; tile select = 20 cndmasks (2-bit tree, static reg indices).
//   h self-loop in LDS: 2 scattered b16 writes (<=2-way banks) -> lgkmcnt
//   (compiler-inserted, same wave) -> 1 b128 read. NO __syncthreads in loop.
//   x-projection off critical path: accx[ts] = bias + W_ih*x_{t+1} via 7
//   independent MFMAs issued during step t's gate math.
// x staged per 8-step chunk into (wave-private) LDS; next chunk's global loads
// held in 7 VGPRs across the chunk to hide HBM latency.

#define T_STEPS 512
#define BATCH   4096
#define IN_F    14
#define HID     28
#define OUT_N   2
#define MB      4                  // batch per wave-block
#define TC      8                  // timesteps per x chunk
#define NCHUNK  (T_STEPS / TC)     // 64
#define HPITCH  40                 // shorts per data row (80 B, 16B-aligned)
#define NTHR    64
#define XREGS   ((MB * TC * IN_F) / NTHR)  // 7 fp32 per thread per chunk
#define NT      7                  // row-tiles (28 units / 4)

typedef __attribute__((ext_vector_type(8))) short  short8;
typedef __attribute__((ext_vector_type(4))) float  float4v;

#define L1 1.4426950408889634f
#define L2 2.8853900817779268f

__device__ __forceinline__ unsigned short f2bf(float f) {
    union { float f; unsigned int u; } v; v.f = f;
    unsigned int r = (v.u + 0x7FFFu + ((v.u >> 16) & 1u)) >> 16;  // RNE
    return (unsigned short)r;
}

__device__ __forceinline__ void gate4(const float4v pr, float& c, float& hf) {
    // pr[0]=i, pr[1]=f, pr[2]=g, pr[3]=o raw preacts
    float ei = __builtin_amdgcn_exp2f(pr[0] * (-L1));
    float ef = __builtin_amdgcn_exp2f(pr[1] * (-L1));
    float eg = __builtin_amdgcn_exp2f(pr[2] * (-L2));
    float eo = __builtin_amdgcn_exp2f(pr[3] * (-L1));
    float av = 1.0f + ei, bv = 1.0f + ef, dv = 1.0f + eg, vv = 1.0f + eo;
    float pd  = av * dv;
    float pqv = pd * bv;
    float rv  = __builtin_amdgcn_rcpf(pqv);
    float sfv = pd * rv;                       // sigma(f)
    float igv = (1.0f - eg) * bv * rv;         // sigma(i)*tanh(g)
    c = fmaf(sfv, c, igv);
    float ec = __builtin_amdgcn_exp2f(c * (-L2));
    float wv = 1.0f + ec;
    float r2 = __builtin_amdgcn_rcpf(vv * wv);
    hf = (1.0f - ec) * r2;                     // sigma(o)*tanh(c)
}

__global__ __launch_bounds__(64, 1)
void lstm_w1(const float* __restrict__ x,
             const float* __restrict__ W_ih,
             const float* __restrict__ W_hh,
             const float* __restrict__ b_ih,
             const float* __restrict__ b_hh,
             const float* __restrict__ W_out,
             const float* __restrict__ b_out,
             float* __restrict__ out) {
    __shared__ __align__(16) short h_a[MB][HPITCH];        // bf16 h (units 0..27; pads 0)
    __shared__ __align__(16) short x_a[TC][MB][HPITCH];    // bf16 x (feats 0..13; pads 0)
    __shared__ float hfin[MB][HID];                        // f32 h for epilogue

    const int l  = threadIdx.x;      // one wave per block
    const int q  = l >> 4;
    const int m  = l & 15;
    const int b3 = m & 3;            // batch (cols duplicate 4x)
    const int cp = m >> 2;           // copy index = owned-tile selector
    const int b0 = blockIdx.x * MB;

    const bool cb0 = (cp & 1) != 0;
    const bool cb1 = (cp & 2) != 0;
    const int  u1  = 4 * cp + q;          // owned unit, first chain (0..15)
    const int  u2  = 16 + 4 * cp + q;     // owned unit, second chain (16..27)
    const bool v2  = (cp < 3);            // second chain valid (tile 4+cp < 7)

    // ---- A-frag weights (bf16) + bias as C-init ----
    // A row r=m of tile ts: gate m&3, unit 4*ts + (m>>2); k = 8q+j.
    short8  Ah[NT], Ax[NT];
    float4v bias[NT];
    #pragma unroll
    for (int ts = 0; ts < NT; ++ts) {
        const int uA   = 4 * ts + cp;                  // 0..27, always valid
        const int wrow = (m & 3) * HID + uA;
        short8 vh, vx;
        #pragma unroll
        for (int j = 0; j < 8; ++j) {
            const int k = 8 * q + j;
            float wh = (k < HID)  ? W_hh[wrow * HID + k]  : 0.0f;
            float wx = (k < IN_F) ? W_ih[wrow * IN_F + k] : 0.0f;
            vh[j] = (short)f2bf(wh);
            vx[j] = (short)f2bf(wx);
        }
        Ah[ts] = vh;
        Ax[ts] = vx;
        // C reg j of tile ts = gate j of unit 4*ts+q, batch m&3
        const int uC = 4 * ts + q;
        float4v bv;
        #pragma unroll
        for (int j = 0; j < 4; ++j)
            bv[j] = b_ih[j * HID + uC] + b_hh[j * HID + uC];
        bias[ts] = bv;
    }

    // ---- zero LDS (h0 = 0; pads stay 0 forever) ----
    for (int k = l; k < MB * HPITCH; k += NTHR) ((short*)h_a)[k] = 0;
    for (int k = l; k < TC * MB * HPITCH; k += NTHR) ((short*)x_a)[k] = 0;

    // ---- prefetch chunk 0 into registers ----
    const float* xbase = x + (long)b0 * T_STEPS * IN_F;
    float xr[XREGS];
    #pragma unroll
    for (int k = 0; k < XREGS; ++k) {
        const int u  = l + NTHR * k;
        const int bb = u / (TC * IN_F);
        const int r  = u - bb * (TC * IN_F);
        xr[k] = xbase[(long)bb * T_STEPS * IN_F + r];
    }

    float c1 = 0.0f, c2 = 0.0f, h1 = 0.0f, h2 = 0.0f;
    float4v accx[NT];

    for (int ch = 0; ch < NCHUNK; ++ch) {
        // stage held registers -> bf16 B-layout (wave-private LDS, no barrier)
        #pragma unroll
        for (int k = 0; k < XREGS; ++k) {
            const int u  = l + NTHR * k;
            const int bb = u / (TC * IN_F);
            const int r  = u - bb * (TC * IN_F);
            const int t  = r / IN_F;
            const int f  = r - t * IN_F;
            x_a[t][bb][f] = (short)f2bf(xr[k]);
        }
        // issue next chunk's global loads (consumed TC steps later)
        if (ch + 1 < NCHUNK) {
            #pragma unroll
            for (int k = 0; k < XREGS; ++k) {
                const int u  = l + NTHR * k;
                const int bb = u / (TC * IN_F);
                const int r  = u - bb * (TC * IN_F);
                xr[k] = xbase[(long)bb * T_STEPS * IN_F + (ch + 1) * TC * IN_F + r];
            }
        }
        // accx for step 0 of this chunk
        {
            short8 bx0 = *(const short8*)&x_a[0][b3][8 * q];
            #pragma unroll
            for (int ts = 0; ts < NT; ++ts)
                accx[ts] = __builtin_amdgcn_mfma_f32_16x16x32_bf16(Ax[ts], bx0, bias[ts], 0, 0, 0);
        }

        #pragma unroll
        for (int tt = 0; tt < TC; ++tt) {
            // h part: 7 independent MFMAs on top of prefetched (bias + x*W_ih)
            short8 bh = *(const short8*)&h_a[b3][8 * q];
            float4v acc[NT];
            #pragma unroll
            for (int ts = 0; ts < NT; ++ts)
                acc[ts] = __builtin_amdgcn_mfma_f32_16x16x32_bf16(Ah[ts], bh, accx[ts], 0, 0, 0);
            // next step's x part — independent, overlaps gate math
            if (tt + 1 < TC) {
                short8 bxn = *(const short8*)&x_a[tt + 1][b3][8 * q];
                #pragma unroll
                for (int ts = 0; ts < NT; ++ts)
                    accx[ts] = __builtin_amdgcn_mfma_f32_16x16x32_bf16(Ax[ts], bxn, bias[ts], 0, 0, 0);
            }
            // select owned tiles (static reg indices, 20 cndmasks)
            float4v a1, a2;
            #pragma unroll
            for (int j = 0; j < 4; ++j) {
                float s01 = cb0 ? acc[1][j] : acc[0][j];
                float s23 = cb0 ? acc[3][j] : acc[2][j];
                a1[j] = cb1 ? s23 : s01;
                float s45 = cb0 ? acc[5][j] : acc[4][j];
                a2[j] = cb1 ? acc[6][j] : s45;     // cp==3 -> garbage, never stored
            }
            gate4(a1, c1, h1);
            gate4(a2, c2, h2);
            // h self-loop writes: banks <=2-way by construction
            ((short*)&h_a[b3][0])[u1] = (short)f2bf(h1);
            if (v2) ((short*)&h_a[b3][0])[u2] = (short)f2bf(h2);
            // compiler inserts lgkmcnt before next step's bh read (same wave)
        }
    }

    // ---- epilogue (wave-internal, no barrier) ----
    hfin[b3][u1] = h1;
    if (v2) hfin[b3][u2] = h2;
    if (l < MB * OUT_N) {
        const int o  = l & 1;
        const int bb = l >> 1;
        float s = b_out[o];
        #pragma unroll
        for (int k = 0; k < HID; ++k)
            s = fmaf(hfin[bb][k], W_out[o * HID + k], s);
        out[(b0 + bb) * OUT_N + o] = s;
    }
}

extern "C" void kernel_launch(void* const* d_in, const int* in_sizes, int n_in,
                              void* d_out, int out_size, void* d_ws, size_t ws_size,
                              hipStream_t stream) {
    const float* x     = (const float*)d_in[0];
    const float* W_ih  = (const float*)d_in[1];
    const float* W_hh  = (const float*)d_in[2];
    const float* b_ih  = (const float*)d_in[3];
    const float* b_hh  = (const float*)d_in[4];
    const float* W_out = (const float*)d_in[5];
    const float* b_out = (const float*)d_in[6];
    float* out = (float*)d_out;

    lstm_w1<<<BATCH / MB, NTHR, 0, stream>>>(
        x, W_ih, W_hh, b_ih, b_hh, W_out, b_out, out);
}

// Round 7
// 272.876 us; speedup vs baseline: 1.2345x; 1.2345x over previous
//
#include <hip/hip_runtime.h>

// LSTM B=4096 T=512 IN=14 H=28 OUT=2, fp32 in/out.
// 8-wave (512thr) fused-gate kernel, grid 256 -> 1 block/CU, 16 batches/CU.
// Waves 0..6 own FOUR units (4w..4w+3) for ALL FOUR gates:
//   A = weights, 16 rows = (gate r&3, unit 4w + (r>>2)); B = data, 16 cols =
//   16 batches. Lane (q,m): C reg j = gate-j preact of unit 4w+q, batch m ->
//   ONE gate4 chain per lane, ONE h-MFMA per wave per step.
// Chain model (~1.5GHz): write-drain + barrier + ds_read + MFMA + gate ->
// every removable piece removed this round:
//   - lgkm-only barriers (asm "s_waitcnt lgkmcnt(0); s_barrier"): global x
//     prefetch loads never drain at barriers (plain __syncthreads forces
//     vmcnt(0) -> chunk-top HBM latency exposure).
//   - h bf16 convert via single v_cvt_pk_bf16_f32 (was 5-op manual RNE).
//   - TC=32: half the chunk-top staging events.
// x-projection off critical path: accx_{t+1} = bias + W_ih*x_{t+1} via an
// independent MFMA during step t (depends only on x_a, prefetched).
// h double-buffered by step parity; ONE barrier per step.

#define T_STEPS 512
#define BATCH   4096
#define IN_F    14
#define HID     28
#define OUT_N   2
#define MB      16                 // batch per block
#define TC      32                 // timesteps per x chunk
#define NCHUNK  (T_STEPS / TC)     // 16
#define HPITCH  40                 // shorts per B-row (80 B, 16B-aligned)
#define NTHR    512
#define XREGS   ((MB * TC * IN_F) / NTHR)   // 14 fp32 per thread per chunk

typedef __attribute__((ext_vector_type(8))) short  short8;
typedef __attribute__((ext_vector_type(4))) float  float4v;

#define L1 1.4426950408889634f
#define L2 2.8853900817779268f

// lgkm-only barrier: LDS writes visible, global loads stay in flight.
#define BARRIER_LGKM() asm volatile("s_waitcnt lgkmcnt(0)\n\ts_barrier" ::: "memory")

__device__ __forceinline__ unsigned short f2bf(float f) {
    union { float f; unsigned int u; } v; v.f = f;
    unsigned int r = (v.u + 0x7FFFu + ((v.u >> 16) & 1u)) >> 16;  // RNE
    return (unsigned short)r;
}

__device__ __forceinline__ unsigned short bf16_1(float f) {
    int r;
    asm("v_cvt_pk_bf16_f32 %0, %1, %2" : "=v"(r) : "v"(f), "v"(f));
    return (unsigned short)(r & 0xFFFF);
}

__device__ __forceinline__ void gate4(const float4v pr, float& c, float& hf) {
    // pr[0]=i, pr[1]=f, pr[2]=g, pr[3]=o raw preacts
    float ei = __builtin_amdgcn_exp2f(pr[0] * (-L1));
    float ef = __builtin_amdgcn_exp2f(pr[1] * (-L1));
    float eg = __builtin_amdgcn_exp2f(pr[2] * (-L2));
    float eo = __builtin_amdgcn_exp2f(pr[3] * (-L1));
    float av = 1.0f + ei, bv = 1.0f + ef, dv = 1.0f + eg, vv = 1.0f + eo;
    float pd  = av * dv;
    float pqv = pd * bv;
    float rv  = __builtin_amdgcn_rcpf(pqv);
    float sfv = pd * rv;                       // sigma(f)
    float igv = (1.0f - eg) * bv * rv;         // sigma(i)*tanh(g)
    c = fmaf(sfv, c, igv);
    float ec = __builtin_amdgcn_exp2f(c * (-L2));
    float wv = 1.0f + ec;
    float r2 = __builtin_amdgcn_rcpf(vv * wv);
    hf = (1.0f - ec) * r2;                     // sigma(o)*tanh(c)
}

__global__ __launch_bounds__(512, 1)
void lstm_f9(const float* __restrict__ x,
             const float* __restrict__ W_ih,
             const float* __restrict__ W_hh,
             const float* __restrict__ b_ih,
             const float* __restrict__ b_hh,
             const float* __restrict__ W_out,
             const float* __restrict__ b_out,
             float* __restrict__ out) {
    __shared__ __align__(16) short h_a[2][MB][HPITCH];         // bf16 h (units 0..27; 28..39 = 0)
    __shared__ __align__(16) short x_a[2][TC][MB][HPITCH];     // bf16 x (feats 0..13; 14..39 = 0)
    __shared__ float hfin[MB][HID];                            // f32 h for epilogue

    const int tid = threadIdx.x;
    const int w   = tid >> 6;        // wave; 0..6 own units [4w, 4w+4)
    const int l   = tid & 63;
    const int q   = l >> 4;
    const int m   = l & 15;          // batch within block (B cols)
    const int b0  = blockIdx.x * MB;
    const bool act = (w < 7);
    const int u   = 4 * w + q;       // unit this lane owns (act only)

    // ---- A-frag weights (bf16) + bias as C-init ----
    // A-frag row = m: gate = m&3, unit = 4w + (m>>2); k = 8q+j.
    short8  Ah = {0,0,0,0,0,0,0,0}, Ax = {0,0,0,0,0,0,0,0};
    float4v bias = {0.0f, 0.0f, 0.0f, 0.0f};
    if (act) {
        const int unit = 4 * w + (m >> 2);               // 0..27, always valid
        const int wrow = (m & 3) * HID + unit;
        #pragma unroll
        for (int j = 0; j < 8; ++j) {
            const int k = 8 * q + j;
            float wh = (k < HID)  ? W_hh[wrow * HID + k]  : 0.0f;
            float wx = (k < IN_F) ? W_ih[wrow * IN_F + k] : 0.0f;
            Ah[j] = (short)f2bf(wh);
            Ax[j] = (short)f2bf(wx);
        }
        // C reg j = gate j of unit u, batch m
        #pragma unroll
        for (int j = 0; j < 4; ++j)
            bias[j] = b_ih[j * HID + u] + b_hh[j * HID + u];
    }

    // ---- zero LDS (h0 = 0; pads stay 0 forever) ----
    for (int k = tid; k < 2 * MB * HPITCH; k += NTHR) ((short*)h_a)[k] = 0;
    for (int k = tid; k < 2 * TC * MB * HPITCH; k += NTHR) ((short*)x_a)[k] = 0;

    // ---- prefetch chunk 0 into registers ----
    const float* xbase = x + (long)b0 * T_STEPS * IN_F;
    float xr[XREGS];
    #pragma unroll
    for (int k = 0; k < XREGS; ++k) {
        const int u2 = tid + NTHR * k;
        const int bb = u2 / (TC * IN_F);
        const int r  = u2 - bb * (TC * IN_F);
        xr[k] = xbase[(long)bb * T_STEPS * IN_F + r];
    }
    BARRIER_LGKM();   // zero-init visible

    float c = 0.0f, hf = 0.0f;
    float4v accx = bias;

    for (int ch = 0; ch < NCHUNK; ++ch) {
        const int buf = ch & 1;
        // convert held registers -> bf16 B-layout for this chunk
        // (compiler inserts the vmcnt wait for xr here; loads landed a chunk ago)
        #pragma unroll
        for (int k = 0; k < XREGS; ++k) {
            const int u2 = tid + NTHR * k;
            const int bb = u2 / (TC * IN_F);
            const int r  = u2 - bb * (TC * IN_F);
            const int t  = r / IN_F;
            const int f  = r - t * IN_F;
            x_a[buf][t][bb][f] = (short)f2bf(xr[k]);
        }
        // issue next chunk's global loads (consumed TC steps later; never
        // drained at barriers thanks to lgkm-only barrier)
        if (ch + 1 < NCHUNK) {
            #pragma unroll
            for (int k = 0; k < XREGS; ++k) {
                const int u2 = tid + NTHR * k;
                const int bb = u2 / (TC * IN_F);
                const int r  = u2 - bb * (TC * IN_F);
                xr[k] = xbase[(long)bb * T_STEPS * IN_F + (ch + 1) * TC * IN_F + r];
            }
        }
        BARRIER_LGKM();   // x_a[buf] visible

        // accx for step 0 of this chunk (once per TC steps on critical path)
        if (act) {
            short8 bx0 = *(const short8*)&x_a[buf][0][m][8 * q];
            accx = __builtin_amdgcn_mfma_f32_16x16x32_bf16(Ax, bx0, bias, 0, 0, 0);
        }

        #pragma unroll
        for (int tt = 0; tt < TC; ++tt) {
            const int rd = tt & 1;               // TC even -> rd=0 at chunk top
            const int wr = rd ^ 1;
            if (act) {
                short8 bh = *(const short8*)&h_a[rd][m][8 * q];
                float4v acc = __builtin_amdgcn_mfma_f32_16x16x32_bf16(Ah, bh, accx, 0, 0, 0);
                // next step's x part — independent, overlaps gate math
                if (tt + 1 < TC) {
                    short8 bxn = *(const short8*)&x_a[buf][tt + 1][m][8 * q];
                    accx = __builtin_amdgcn_mfma_f32_16x16x32_bf16(Ax, bxn, bias, 0, 0, 0);
                }
                // lane (q,m): acc[j] = gate-j preact of unit u, batch m
                gate4(acc, c, hf);
                ((short*)&h_a[wr][m][0])[u] = (short)bf16_1(hf);
            }
            BARRIER_LGKM();   // h_{t+1} visible
        }
    }

    // ---- epilogue: out[b][o] = h_T[b] . W_out[o] + b_out[o] ----
    if (act) hfin[m][u] = hf;
    BARRIER_LGKM();
    if (tid < MB * OUT_N) {
        const int o  = tid & 1;
        const int bb = tid >> 1;
        float s = b_out[o];
        #pragma unroll
        for (int k = 0; k < HID; ++k)
            s = fmaf(hfin[bb][k], W_out[o * HID + k], s);
        out[(b0 + bb) * OUT_N + o] = s;
    }
}

extern "C" void kernel_launch(void* const* d_in, const int* in_sizes, int n_in,
                              void* d_out, int out_size, void* d_ws, size_t ws_size,
                              hipStream_t stream) {
    const float* x     = (const float*)d_in[0];
    const float* W_ih  = (const float*)d_in[1];
    const float* W_hh  = (const float*)d_in[2];
    const float* b_ih  = (const float*)d_in[3];
    const float* b_hh  = (const float*)d_in[4];
    const float* W_out = (const float*)d_in[5];
    const float* b_out = (const float*)d_in[6];
    float* out = (float*)d_out;

    lstm_f9<<<BATCH / MB, NTHR, 0, stream>>>(
        x, W_ih, W_hh, b_ih, b_hh, W_out, b_out, out);
}